// Round 5
// baseline (203.918 us; speedup 1.0000x reference)
//
#include <hip/hip_runtime.h>

#define NN 50000
#define NE 800000
#define KC 512
#define OC 256  // 128 mu cols | 128 logstd cols
#define NB_SCAN 196  // ceil(NN/256)

typedef float f32x4 __attribute__((ext_vector_type(4)));
typedef short bf16x8 __attribute__((ext_vector_type(8)));

__device__ __forceinline__ unsigned f2bf(float f) {
    union { float f; unsigned u; } v; v.f = f;
    return (v.u + 0x7FFFu + ((v.u >> 16) & 1u)) >> 16;  // RNE
}
__device__ __forceinline__ float bf2f(unsigned short b) {
    union { unsigned u; float f; } v; v.u = ((unsigned)b) << 16;
    return v.f;
}

// ---------------- degree count ----------------
__global__ __launch_bounds__(256) void count_deg_kernel(const int* __restrict__ ei,
                                                        int* __restrict__ deg) {
    int e = blockIdx.x * 256 + threadIdx.x;
    if (e < NE) atomicAdd(&deg[ei[NE + e]], 1);
}

// ---------------- hierarchical scan: A) per-block sums ----------------
__global__ __launch_bounds__(256) void scan_part_kernel(const int* __restrict__ deg,
                                                        int* __restrict__ partial) {
    int tid = threadIdx.x;
    int i = blockIdx.x * 256 + tid;
    int v = (i < NN) ? deg[i] : 0;
#pragma unroll
    for (int off = 32; off > 0; off >>= 1) v += __shfl_down(v, off, 64);
    __shared__ int wsum[4];
    if ((tid & 63) == 0) wsum[tid >> 6] = v;
    __syncthreads();
    if (tid == 0) partial[blockIdx.x] = wsum[0] + wsum[1] + wsum[2] + wsum[3];
}

// ---------------- B) scan the 196 partials (one tiny block) ----------------
__global__ __launch_bounds__(256) void scan_block_kernel(const int* __restrict__ partial,
                                                         int* __restrict__ blockoff) {
    __shared__ int lds[256];
    int tid = threadIdx.x;
    int v = (tid < NB_SCAN) ? partial[tid] : 0;
    lds[tid] = v;
    __syncthreads();
    for (int off = 1; off < 256; off <<= 1) {
        int t = (tid >= off) ? lds[tid - off] : 0;
        __syncthreads();
        lds[tid] += t;
        __syncthreads();
    }
    if (tid < NB_SCAN) blockoff[tid] = lds[tid] - v;  // exclusive
}

// ---------------- C) apply: block-local scan + offset, emit CSR ptrs + dinv ----------------
__global__ __launch_bounds__(256) void scan_apply_kernel(const int* __restrict__ deg,
                                                         const int* __restrict__ blockoff,
                                                         int* __restrict__ row_start,
                                                         int* __restrict__ cursor,
                                                         float* __restrict__ dinv) {
    int tid = threadIdx.x;
    int lane = tid & 63;
    int w = tid >> 6;
    int i = blockIdx.x * 256 + tid;
    int d = (i < NN) ? deg[i] : 0;
    int v = d;
#pragma unroll
    for (int off = 1; off < 64; off <<= 1) {
        int t = __shfl_up(v, off, 64);
        if (lane >= off) v += t;
    }
    __shared__ int wsum[4];
    if (lane == 63) wsum[w] = v;
    __syncthreads();
    int wof = 0;
    for (int k = 0; k < w; ++k) wof += wsum[k];
    int excl = blockoff[blockIdx.x] + wof + v - d;
    if (i < NN) {
        row_start[i] = excl;
        cursor[i] = excl;
        dinv[i] = rsqrtf((float)(d + 1));  // +1 self-loop
    }
    if (i == NN - 1) row_start[NN] = excl + d;
}

// ---------------- scatter edges into CSR (by dst) ----------------
__global__ __launch_bounds__(256) void scatter_kernel(const int* __restrict__ ei,
                                                      int* __restrict__ cursor,
                                                      int* __restrict__ csr_src) {
    int e = blockIdx.x * 256 + threadIdx.x;
    if (e < NE) {
        int d = ei[NE + e];
        int pos = atomicAdd(&cursor[d], 1);
        csr_src[pos] = ei[e];
    }
}

// ---------------- W -> fused bf16, wave-fragment-contiguous layout ----------------
// Slot index = kb*1024 + wf*64 + lane, wf=w*4+fc, lane=g4*16+i16.
// Holds W[k = kb*32+g4*8 .. +7][col = (wf>>2)*64 + (wf&3)*16 + i16] as 8 bf16.
__global__ __launch_bounds__(256) void convw_kernel(const float* __restrict__ Wmu,
                                                    const float* __restrict__ Wls,
                                                    uint4* __restrict__ Wc) {
    int idx = blockIdx.x * 256 + threadIdx.x;  // 16384 slots
    int kb = idx >> 10;
    int rem = idx & 1023;
    int wf = rem >> 6;
    int lane = rem & 63;
    int g4 = lane >> 4;
    int i16 = lane & 15;
    int col = (wf >> 2) * 64 + (wf & 3) * 16 + i16;
    int k0 = kb * 32 + g4 * 8;
    const float* Wsrc = (col < 128) ? (Wmu + col) : (Wls + (col - 128));
    unsigned o[4];
#pragma unroll
    for (int p = 0; p < 4; ++p) {
        float lo = Wsrc[(size_t)(k0 + 2 * p) * 128];
        float hi = Wsrc[(size_t)(k0 + 2 * p + 1) * 128];
        o[p] = f2bf(lo) | (f2bf(hi) << 16);
    }
    uint4 v;
    v.x = o[0]; v.y = o[1]; v.z = o[2]; v.w = o[3];
    Wc[idx] = v;
}

// ---------------- MFMA GEMM: hs[N][256] = bf16(x @ [Wmu|Wls]) * dinv[row] ----------------
// BM=64, 4 waves. A: LDS super-steps of 128 k (double-buffered, 1 barrier/super).
// B: register double-buffer straight from L2 (Wc is 256 KB, L2-resident).
#define ALD 136  // ushort stride per A row (272 B): bank-conflict-free reads+writes
__global__ __launch_bounds__(256) void gemm_kernel(const float* __restrict__ x,
                                                   const uint4* __restrict__ Wc,
                                                   const float* __restrict__ dinv,
                                                   unsigned short* __restrict__ hs) {
    __shared__ __align__(16) unsigned short As[2][64 * ALD];

    int tid = threadIdx.x;
    int lane = tid & 63;
    int w = tid >> 6;
    int r0 = blockIdx.x * 64;
    int i16 = lane & 15;
    int g4 = lane >> 4;

    // A staging: thread t owns row t>>2, 128-byte k-chunk (t&3) of each super-step
    int st_row = tid >> 2;
    int st_c = tid & 3;
    int xr = r0 + st_row;
    if (xr > NN - 1) xr = NN - 1;
    const float* xg = x + (size_t)xr * KC + st_c * 32;
    unsigned short* adst = &As[0][st_row * ALD + st_c * 32];

    float4 xa[8];
    auto loadA = [&](int S) {
#pragma unroll
        for (int i = 0; i < 8; ++i) xa[i] = *(const float4*)(xg + S * 128 + i * 4);
    };
    auto storeA = [&](int buf) {
        uint4* dst = (uint4*)(adst + buf * 64 * ALD);
#pragma unroll
        for (int p = 0; p < 4; ++p) {
            uint4 o;
            o.x = f2bf(xa[2 * p].x) | (f2bf(xa[2 * p].y) << 16);
            o.y = f2bf(xa[2 * p].z) | (f2bf(xa[2 * p].w) << 16);
            o.z = f2bf(xa[2 * p + 1].x) | (f2bf(xa[2 * p + 1].y) << 16);
            o.w = f2bf(xa[2 * p + 1].z) | (f2bf(xa[2 * p + 1].w) << 16);
            dst[p] = o;
        }
    };

    // B: wave w's 4 fragments for k-step kb live at Wc[kb*1024 + (w*4+fc)*64 + lane]
    const uint4* wbase = Wc + (size_t)(w * 4) * 64 + lane;
    uint4 bb[2][4];
    auto loadB = [&](int dbuf, int kb) {
#pragma unroll
        for (int fc = 0; fc < 4; ++fc) bb[dbuf][fc] = wbase[kb * 1024 + fc * 64];
    };

    f32x4 acc[4][4];
    f32x4 zz = {0.f, 0.f, 0.f, 0.f};
#pragma unroll
    for (int a = 0; a < 4; ++a)
#pragma unroll
        for (int b = 0; b < 4; ++b) acc[a][b] = zz;

    loadA(0);
    storeA(0);
    __syncthreads();
    loadA(1);        // prefetch next super (has ~4 k-steps of MFMA to land)
    loadB(0, 0);     // prefetch first k-step's B

#pragma unroll
    for (int S = 0; S < 4; ++S) {
#pragma unroll
        for (int ks = 0; ks < 4; ++ks) {
            const int kb = S * 4 + ks;
            const int cur = kb & 1;
            if (kb < 15) loadB(cur ^ 1, kb + 1);
            bf16x8 af[4];
#pragma unroll
            for (int fr = 0; fr < 4; ++fr)
                af[fr] = *(const bf16x8*)&As[S & 1][(fr * 16 + i16) * ALD + ks * 32 + g4 * 8];
#pragma unroll
            for (int fc = 0; fc < 4; ++fc) {
                bf16x8 bfrag = *(const bf16x8*)&bb[cur][fc];
#pragma unroll
                for (int fr = 0; fr < 4; ++fr)
                    acc[fr][fc] = __builtin_amdgcn_mfma_f32_16x16x32_bf16(af[fr], bfrag, acc[fr][fc], 0, 0, 0);
            }
        }
        if (S < 3) {
            storeA((S + 1) & 1);  // xa(S+1) arrived during this super's MFMAs
            __syncthreads();
            if (S < 2) loadA(S + 2);
        }
    }

    // epilogue: C/D layout col=lane&15, row=(lane>>4)*4+reg (m89); scale by dinv
#pragma unroll
    for (int fr = 0; fr < 4; ++fr) {
#pragma unroll
        for (int r = 0; r < 4; ++r) {
            int gr = r0 + fr * 16 + g4 * 4 + r;
            if (gr < NN) {
                float dv = dinv[gr];
#pragma unroll
                for (int fc = 0; fc < 4; ++fc) {
                    int col = w * 64 + fc * 16 + i16;
                    hs[(size_t)gr * OC + col] = (unsigned short)f2bf(acc[fr][fc][r] * dv);
                }
            }
        }
    }
}

// ---------------- aggregation: out = dinv[n]*(sum_e hs[src] + hs[n]) + b ----------------
__global__ __launch_bounds__(256) void aggregate_kernel(const unsigned short* __restrict__ hs,
                                                        const int* __restrict__ row_start,
                                                        const int* __restrict__ csr_src,
                                                        const float* __restrict__ dinv,
                                                        const float* __restrict__ bmu,
                                                        const float* __restrict__ bls,
                                                        float* __restrict__ out) {
    int tid = threadIdx.x;
    int lane = tid & 63;
    int node = blockIdx.x * 4 + (tid >> 6);

    const unsigned short* hrow = hs + lane * 4;  // lane covers cols 4l..4l+3
    float acc0, acc1, acc2, acc3;
    {
        ushort4 v = *(const ushort4*)&hrow[(size_t)node * OC];
        acc0 = bf2f(v.x);
        acc1 = bf2f(v.y);
        acc2 = bf2f(v.z);
        acc3 = bf2f(v.w);
    }
    int rs = row_start[node], re = row_start[node + 1];
    int e = rs;
    for (; e + 8 <= re; e += 8) {
        int s[8];
#pragma unroll
        for (int q = 0; q < 8; ++q) s[q] = csr_src[e + q];
        ushort4 v[8];
#pragma unroll
        for (int q = 0; q < 8; ++q) v[q] = *(const ushort4*)&hrow[(size_t)s[q] * OC];
#pragma unroll
        for (int q = 0; q < 8; ++q) {
            acc0 += bf2f(v[q].x);
            acc1 += bf2f(v[q].y);
            acc2 += bf2f(v[q].z);
            acc3 += bf2f(v[q].w);
        }
    }
    if (e + 4 <= re) {
        int s[4];
#pragma unroll
        for (int q = 0; q < 4; ++q) s[q] = csr_src[e + q];
        ushort4 v[4];
#pragma unroll
        for (int q = 0; q < 4; ++q) v[q] = *(const ushort4*)&hrow[(size_t)s[q] * OC];
#pragma unroll
        for (int q = 0; q < 4; ++q) {
            acc0 += bf2f(v[q].x);
            acc1 += bf2f(v[q].y);
            acc2 += bf2f(v[q].z);
            acc3 += bf2f(v[q].w);
        }
        e += 4;
    }
    for (; e < re; ++e) {
        int s0 = csr_src[e];
        ushort4 v0 = *(const ushort4*)&hrow[(size_t)s0 * OC];
        acc0 += bf2f(v0.x);
        acc1 += bf2f(v0.y);
        acc2 += bf2f(v0.z);
        acc3 += bf2f(v0.w);
    }
    float dn = dinv[node];
    if (lane < 32) {
        float4 b = ((const float4*)bmu)[lane];
        float4 r = {acc0 * dn + b.x, acc1 * dn + b.y, acc2 * dn + b.z, acc3 * dn + b.w};
        ((float4*)out)[(size_t)node * 32 + lane] = r;
    } else {
        float4 b = ((const float4*)bls)[lane - 32];
        float4 r = {acc0 * dn + b.x, acc1 * dn + b.y, acc2 * dn + b.z, acc3 * dn + b.w};
        ((float4*)out)[(size_t)(NN + node) * 32 + (lane - 32)] = r;
    }
}

extern "C" void kernel_launch(void* const* d_in, const int* in_sizes, int n_in,
                              void* d_out, int out_size, void* d_ws, size_t ws_size,
                              hipStream_t stream) {
    const float* x = (const float*)d_in[0];
    const int* ei = (const int*)d_in[1];  // [2][NE]: src then dst
    const float* Wmu = (const float*)d_in[2];
    const float* bmu = (const float*)d_in[3];
    const float* Wls = (const float*)d_in[4];
    const float* bls = (const float*)d_in[5];
    float* out = (float*)d_out;

    char* ws = (char*)d_ws;
    size_t off = 0;
    auto alloc = [&](size_t bytes) {
        void* p = ws + off;
        off += (bytes + 255) & ~(size_t)255;
        return p;
    };
    unsigned short* hs = (unsigned short*)alloc((size_t)NN * OC * sizeof(unsigned short));  // 25.6 MB
    uint4* Wc = (uint4*)alloc((size_t)16384 * 16);                                          // 256 KB
    int* deg = (int*)alloc((size_t)NN * sizeof(int));
    int* row_start = (int*)alloc((size_t)(NN + 1) * sizeof(int));
    int* cursor = (int*)alloc((size_t)NN * sizeof(int));
    int* csr_src = (int*)alloc((size_t)NE * sizeof(int));
    float* dinv = (float*)alloc((size_t)NN * sizeof(float));
    int* partial = (int*)alloc((size_t)NB_SCAN * sizeof(int));
    int* blockoff = (int*)alloc((size_t)NB_SCAN * sizeof(int));

    hipMemsetAsync(deg, 0, (size_t)NN * sizeof(int), stream);

    count_deg_kernel<<<(NE + 255) / 256, 256, 0, stream>>>(ei, deg);
    scan_part_kernel<<<NB_SCAN, 256, 0, stream>>>(deg, partial);
    scan_block_kernel<<<1, 256, 0, stream>>>(partial, blockoff);
    scan_apply_kernel<<<NB_SCAN, 256, 0, stream>>>(deg, blockoff, row_start, cursor, dinv);
    scatter_kernel<<<(NE + 255) / 256, 256, 0, stream>>>(ei, cursor, csr_src);
    convw_kernel<<<64, 256, 0, stream>>>(Wmu, Wls, Wc);
    gemm_kernel<<<(NN + 63) / 64, 256, 0, stream>>>(x, Wc, dinv, hs);
    aggregate_kernel<<<NN / 4, 256, 0, stream>>>(hs, row_start, csr_src, dinv, bmu, bls, out);
}

// Round 6
// 200.572 us; speedup vs baseline: 1.0167x; 1.0167x over previous
//
#include <hip/hip_runtime.h>

#define NN 50000
#define NE 800000
#define KC 512
#define OC 256  // 128 mu cols | 128 logstd cols
#define NB_SCAN 196  // ceil(NN/256)

typedef float f32x4 __attribute__((ext_vector_type(4)));
typedef short bf16x8 __attribute__((ext_vector_type(8)));

__device__ __forceinline__ unsigned f2bf(float f) {
    union { float f; unsigned u; } v; v.f = f;
    return (v.u + 0x7FFFu + ((v.u >> 16) & 1u)) >> 16;  // RNE
}
__device__ __forceinline__ float bf2f(unsigned short b) {
    union { unsigned u; float f; } v; v.u = ((unsigned)b) << 16;
    return v.f;
}

// ---------------- degree count ----------------
__global__ __launch_bounds__(256) void count_deg_kernel(const int* __restrict__ ei,
                                                        int* __restrict__ deg) {
    int e = blockIdx.x * 256 + threadIdx.x;
    if (e < NE) atomicAdd(&deg[ei[NE + e]], 1);
}

// ---------------- hierarchical scan: A) per-block sums ----------------
__global__ __launch_bounds__(256) void scan_part_kernel(const int* __restrict__ deg,
                                                        int* __restrict__ partial) {
    int tid = threadIdx.x;
    int i = blockIdx.x * 256 + tid;
    int v = (i < NN) ? deg[i] : 0;
#pragma unroll
    for (int off = 32; off > 0; off >>= 1) v += __shfl_down(v, off, 64);
    __shared__ int wsum[4];
    if ((tid & 63) == 0) wsum[tid >> 6] = v;
    __syncthreads();
    if (tid == 0) partial[blockIdx.x] = wsum[0] + wsum[1] + wsum[2] + wsum[3];
}

// ---------------- B) scan the 196 partials (one tiny block) ----------------
__global__ __launch_bounds__(256) void scan_block_kernel(const int* __restrict__ partial,
                                                         int* __restrict__ blockoff) {
    __shared__ int lds[256];
    int tid = threadIdx.x;
    int v = (tid < NB_SCAN) ? partial[tid] : 0;
    lds[tid] = v;
    __syncthreads();
    for (int off = 1; off < 256; off <<= 1) {
        int t = (tid >= off) ? lds[tid - off] : 0;
        __syncthreads();
        lds[tid] += t;
        __syncthreads();
    }
    if (tid < NB_SCAN) blockoff[tid] = lds[tid] - v;  // exclusive
}

// ---------------- C) apply: block-local scan + offset, emit CSR ptrs + dinv ----------------
__global__ __launch_bounds__(256) void scan_apply_kernel(const int* __restrict__ deg,
                                                         const int* __restrict__ blockoff,
                                                         int* __restrict__ row_start,
                                                         int* __restrict__ cursor,
                                                         float* __restrict__ dinv) {
    int tid = threadIdx.x;
    int lane = tid & 63;
    int w = tid >> 6;
    int i = blockIdx.x * 256 + tid;
    int d = (i < NN) ? deg[i] : 0;
    int v = d;
#pragma unroll
    for (int off = 1; off < 64; off <<= 1) {
        int t = __shfl_up(v, off, 64);
        if (lane >= off) v += t;
    }
    __shared__ int wsum[4];
    if (lane == 63) wsum[w] = v;
    __syncthreads();
    int wof = 0;
    for (int k = 0; k < w; ++k) wof += wsum[k];
    int excl = blockoff[blockIdx.x] + wof + v - d;
    if (i < NN) {
        row_start[i] = excl;
        cursor[i] = excl;
        dinv[i] = rsqrtf((float)(d + 1));  // +1 self-loop
    }
    if (i == NN - 1) row_start[NN] = excl + d;
}

// ---------------- scatter edges into CSR (by dst) ----------------
__global__ __launch_bounds__(256) void scatter_kernel(const int* __restrict__ ei,
                                                      int* __restrict__ cursor,
                                                      int* __restrict__ csr_src) {
    int e = blockIdx.x * 256 + threadIdx.x;
    if (e < NE) {
        int d = ei[NE + e];
        int pos = atomicAdd(&cursor[d], 1);
        csr_src[pos] = ei[e];
    }
}

// ---------------- W -> fused bf16, wave-fragment-contiguous layout ----------------
// Slot index = kb*1024 + wf*64 + lane, wf=w*4+fc, lane=g4*16+i16.
// Holds W[k = kb*32+g4*8 .. +7][col = (wf>>2)*64 + (wf&3)*16 + i16] as 8 bf16.
__global__ __launch_bounds__(256) void convw_kernel(const float* __restrict__ Wmu,
                                                    const float* __restrict__ Wls,
                                                    uint4* __restrict__ Wc) {
    int idx = blockIdx.x * 256 + threadIdx.x;  // 16384 slots
    int kb = idx >> 10;
    int rem = idx & 1023;
    int wf = rem >> 6;
    int lane = rem & 63;
    int g4 = lane >> 4;
    int i16 = lane & 15;
    int col = (wf >> 2) * 64 + (wf & 3) * 16 + i16;
    int k0 = kb * 32 + g4 * 8;
    const float* Wsrc = (col < 128) ? (Wmu + col) : (Wls + (col - 128));
    unsigned o[4];
#pragma unroll
    for (int p = 0; p < 4; ++p) {
        float lo = Wsrc[(size_t)(k0 + 2 * p) * 128];
        float hi = Wsrc[(size_t)(k0 + 2 * p + 1) * 128];
        o[p] = f2bf(lo) | (f2bf(hi) << 16);
    }
    uint4 v;
    v.x = o[0]; v.y = o[1]; v.z = o[2]; v.w = o[3];
    Wc[idx] = v;
}

// ---------------- MFMA GEMM: hs[N][256] = bf16(x @ [Wmu|Wls]) * dinv[row] ----------------
// BM=32 (grid 1563 -> ~6 blocks/CU for occupancy), 4 waves; wave w: 32 rows x cols w*64..+63.
// A: LDS super-steps of 128 k, double-buffered. B: register double-buffer from L2 Wc.
#define ALD 136  // ushort stride per A row (272 B)
__global__ __launch_bounds__(256, 4) void gemm_kernel(const float* __restrict__ x,
                                                      const uint4* __restrict__ Wc,
                                                      const float* __restrict__ dinv,
                                                      unsigned short* __restrict__ hs) {
    __shared__ __align__(16) unsigned short As[2][32 * ALD];

    int tid = threadIdx.x;
    int lane = tid & 63;
    int w = tid >> 6;
    int r0 = blockIdx.x * 32;
    int i16 = lane & 15;
    int g4 = lane >> 4;

    // A staging: thread t owns row t>>3 (0..31), 64-byte chunk t&7 of each 128-k super-step
    int st_row = tid >> 3;
    int st_c = tid & 7;
    int xr = r0 + st_row;
    if (xr > NN - 1) xr = NN - 1;
    const float* xg = x + (size_t)xr * KC + st_c * 16;
    unsigned short* adst = &As[0][st_row * ALD + st_c * 16];

    float4 xa[4];
    auto loadA = [&](int S) {
#pragma unroll
        for (int i = 0; i < 4; ++i) xa[i] = *(const float4*)(xg + S * 128 + i * 4);
    };
    auto storeA = [&](int buf) {
        uint4* dst = (uint4*)(adst + buf * 32 * ALD);
#pragma unroll
        for (int p = 0; p < 2; ++p) {
            uint4 o;
            o.x = f2bf(xa[2 * p].x) | (f2bf(xa[2 * p].y) << 16);
            o.y = f2bf(xa[2 * p].z) | (f2bf(xa[2 * p].w) << 16);
            o.z = f2bf(xa[2 * p + 1].x) | (f2bf(xa[2 * p + 1].y) << 16);
            o.w = f2bf(xa[2 * p + 1].z) | (f2bf(xa[2 * p + 1].w) << 16);
            dst[p] = o;
        }
    };

    // B: wave w's 4 fragments for k-step kb at Wc[kb*1024 + (w*4+fc)*64 + lane]
    const uint4* wbase = Wc + (size_t)(w * 4) * 64 + lane;
    uint4 bb[2][4];
    auto loadB = [&](int dbuf, int kb) {
#pragma unroll
        for (int fc = 0; fc < 4; ++fc) bb[dbuf][fc] = wbase[kb * 1024 + fc * 64];
    };

    f32x4 acc[2][4];
    f32x4 zz = {0.f, 0.f, 0.f, 0.f};
#pragma unroll
    for (int a = 0; a < 2; ++a)
#pragma unroll
        for (int b = 0; b < 4; ++b) acc[a][b] = zz;

    loadA(0);
    storeA(0);
    __syncthreads();
    loadA(1);        // prefetch next super-step
    loadB(0, 0);     // prefetch first k-step's B

#pragma unroll
    for (int S = 0; S < 4; ++S) {
#pragma unroll
        for (int ks = 0; ks < 4; ++ks) {
            const int kb = S * 4 + ks;
            const int cur = kb & 1;
            if (kb < 15) loadB(cur ^ 1, kb + 1);
            bf16x8 af[2];
#pragma unroll
            for (int fr = 0; fr < 2; ++fr)
                af[fr] = *(const bf16x8*)&As[S & 1][(fr * 16 + i16) * ALD + ks * 32 + g4 * 8];
#pragma unroll
            for (int fc = 0; fc < 4; ++fc) {
                bf16x8 bfrag = *(const bf16x8*)&bb[cur][fc];
#pragma unroll
                for (int fr = 0; fr < 2; ++fr)
                    acc[fr][fc] = __builtin_amdgcn_mfma_f32_16x16x32_bf16(af[fr], bfrag, acc[fr][fc], 0, 0, 0);
            }
        }
        if (S < 3) {
            storeA((S + 1) & 1);  // xa(S+1) arrived during this super's MFMAs
            __syncthreads();
            if (S < 2) loadA(S + 2);
        }
    }

    // epilogue: C/D layout col=lane&15, row=(lane>>4)*4+reg (m89); scale by dinv
#pragma unroll
    for (int fr = 0; fr < 2; ++fr) {
#pragma unroll
        for (int r = 0; r < 4; ++r) {
            int gr = r0 + fr * 16 + g4 * 4 + r;
            if (gr < NN) {
                float dv = dinv[gr];
#pragma unroll
                for (int fc = 0; fc < 4; ++fc) {
                    int col = w * 64 + fc * 16 + i16;
                    hs[(size_t)gr * OC + col] = (unsigned short)f2bf(acc[fr][fc][r] * dv);
                }
            }
        }
    }
}

// ---------------- aggregation: out = dinv[n]*(sum_e hs[src] + hs[n]) + b ----------------
__global__ __launch_bounds__(256) void aggregate_kernel(const unsigned short* __restrict__ hs,
                                                        const int* __restrict__ row_start,
                                                        const int* __restrict__ csr_src,
                                                        const float* __restrict__ dinv,
                                                        const float* __restrict__ bmu,
                                                        const float* __restrict__ bls,
                                                        float* __restrict__ out) {
    int tid = threadIdx.x;
    int lane = tid & 63;
    int node = blockIdx.x * 4 + (tid >> 6);

    const unsigned short* hrow = hs + lane * 4;  // lane covers cols 4l..4l+3
    float acc0, acc1, acc2, acc3;
    {
        ushort4 v = *(const ushort4*)&hrow[(size_t)node * OC];
        acc0 = bf2f(v.x);
        acc1 = bf2f(v.y);
        acc2 = bf2f(v.z);
        acc3 = bf2f(v.w);
    }
    int rs = row_start[node], re = row_start[node + 1];
    int e = rs;
    for (; e + 8 <= re; e += 8) {
        int s[8];
#pragma unroll
        for (int q = 0; q < 8; ++q) s[q] = csr_src[e + q];
        ushort4 v[8];
#pragma unroll
        for (int q = 0; q < 8; ++q) v[q] = *(const ushort4*)&hrow[(size_t)s[q] * OC];
#pragma unroll
        for (int q = 0; q < 8; ++q) {
            acc0 += bf2f(v[q].x);
            acc1 += bf2f(v[q].y);
            acc2 += bf2f(v[q].z);
            acc3 += bf2f(v[q].w);
        }
    }
    if (e + 4 <= re) {
        int s[4];
#pragma unroll
        for (int q = 0; q < 4; ++q) s[q] = csr_src[e + q];
        ushort4 v[4];
#pragma unroll
        for (int q = 0; q < 4; ++q) v[q] = *(const ushort4*)&hrow[(size_t)s[q] * OC];
#pragma unroll
        for (int q = 0; q < 4; ++q) {
            acc0 += bf2f(v[q].x);
            acc1 += bf2f(v[q].y);
            acc2 += bf2f(v[q].z);
            acc3 += bf2f(v[q].w);
        }
        e += 4;
    }
    for (; e < re; ++e) {
        int s0 = csr_src[e];
        ushort4 v0 = *(const ushort4*)&hrow[(size_t)s0 * OC];
        acc0 += bf2f(v0.x);
        acc1 += bf2f(v0.y);
        acc2 += bf2f(v0.z);
        acc3 += bf2f(v0.w);
    }
    float dn = dinv[node];
    if (lane < 32) {
        float4 b = ((const float4*)bmu)[lane];
        float4 r = {acc0 * dn + b.x, acc1 * dn + b.y, acc2 * dn + b.z, acc3 * dn + b.w};
        ((float4*)out)[(size_t)node * 32 + lane] = r;
    } else {
        float4 b = ((const float4*)bls)[lane - 32];
        float4 r = {acc0 * dn + b.x, acc1 * dn + b.y, acc2 * dn + b.z, acc3 * dn + b.w};
        ((float4*)out)[(size_t)(NN + node) * 32 + (lane - 32)] = r;
    }
}

extern "C" void kernel_launch(void* const* d_in, const int* in_sizes, int n_in,
                              void* d_out, int out_size, void* d_ws, size_t ws_size,
                              hipStream_t stream) {
    const float* x = (const float*)d_in[0];
    const int* ei = (const int*)d_in[1];  // [2][NE]: src then dst
    const float* Wmu = (const float*)d_in[2];
    const float* bmu = (const float*)d_in[3];
    const float* Wls = (const float*)d_in[4];
    const float* bls = (const float*)d_in[5];
    float* out = (float*)d_out;

    char* ws = (char*)d_ws;
    size_t off = 0;
    auto alloc = [&](size_t bytes) {
        void* p = ws + off;
        off += (bytes + 255) & ~(size_t)255;
        return p;
    };
    unsigned short* hs = (unsigned short*)alloc((size_t)NN * OC * sizeof(unsigned short));  // 25.6 MB
    uint4* Wc = (uint4*)alloc((size_t)16384 * 16);                                          // 256 KB
    int* deg = (int*)alloc((size_t)NN * sizeof(int));
    int* row_start = (int*)alloc((size_t)(NN + 1) * sizeof(int));
    int* cursor = (int*)alloc((size_t)NN * sizeof(int));
    int* csr_src = (int*)alloc((size_t)NE * sizeof(int));
    float* dinv = (float*)alloc((size_t)NN * sizeof(float));
    int* partial = (int*)alloc((size_t)NB_SCAN * sizeof(int));
    int* blockoff = (int*)alloc((size_t)NB_SCAN * sizeof(int));

    hipMemsetAsync(deg, 0, (size_t)NN * sizeof(int), stream);

    count_deg_kernel<<<(NE + 255) / 256, 256, 0, stream>>>(ei, deg);
    scan_part_kernel<<<NB_SCAN, 256, 0, stream>>>(deg, partial);
    scan_block_kernel<<<1, 256, 0, stream>>>(partial, blockoff);
    scan_apply_kernel<<<NB_SCAN, 256, 0, stream>>>(deg, blockoff, row_start, cursor, dinv);
    scatter_kernel<<<(NE + 255) / 256, 256, 0, stream>>>(ei, cursor, csr_src);
    convw_kernel<<<64, 256, 0, stream>>>(Wmu, Wls, Wc);
    gemm_kernel<<<(NN + 31) / 32, 256, 0, stream>>>(x, Wc, dinv, hs);
    aggregate_kernel<<<NN / 4, 256, 0, stream>>>(hs, row_start, csr_src, dinv, bmu, bls, out);
}